// Round 2
// baseline (376.114 us; speedup 1.0000x reference)
//
#include <hip/hip_runtime.h>
#include <hip/hip_bf16.h>

// S2Conv: x (512,64,121) f32, w (64,64,512) f32, Y (512,121) f32
// out (512,64,1771) f32.
// psi[e,g,i] = sum_n Y[n,i] w[e,g,n] / sqrt(512)
// out[b,g, OFF_l + u*d + m] = (1/8) sum_e psi[e,g,l^2+u] * x[b,e,l^2+m]
//
// Round 2: conv retiled to (g,b)-ALIGNED tiles (templated on l -> all divs are
// compile-time magic), accumulators staged in LDS, epilogue writes complete d^2
// blocks per (b,g) as fully-coalesced 256B/instr runs. Bijective XCD swizzle
// for x_t L2 residency. MFMA accumulation order per output unchanged ->
// bit-identical results vs round 1.

#define OUTROW 1771
#define OUTB   113344  // 64*1771

typedef __attribute__((ext_vector_type(8))) short bf16x8;
typedef __attribute__((ext_vector_type(4))) float floatx4;

// cumulative conv block counts per l (NGT*NBT): {2,28,66,120,190,299,432,496,770,880,946}
__device__ __constant__ int c_blk[12] = {0,2,30,96,216,406,705,1137,1633,2403,3283,4229};
__device__ __constant__ signed char c_ltab[121] = {
  0,
  1,1,1,
  2,2,2,2,2,
  3,3,3,3,3,3,3,
  4,4,4,4,4,4,4,4,4,
  5,5,5,5,5,5,5,5,5,5,5,
  6,6,6,6,6,6,6,6,6,6,6,6,6,
  7,7,7,7,7,7,7,7,7,7,7,7,7,7,7,
  8,8,8,8,8,8,8,8,8,8,8,8,8,8,8,8,8,
  9,9,9,9,9,9,9,9,9,9,9,9,9,9,9,9,9,9,9,
  10,10,10,10,10,10,10,10,10,10,10,10,10,10,10,10,10,10,10,10,10
};

// ---------------------------------------------------------------------------
// Prep (unchanged from round 1): blocks [0,64): psi via MFMA, one block per g.
//                                blocks [64,576): x_t transpose, one block per b.
// psi_t[64*l^2 + g*d + u][e] = scale * sum_n w[e,g,n]*Y[n,l^2+u]   (bf16)
// x_t [512*l^2 + b*d + m][e] = x[b,e,l^2+m]                        (bf16)
// ---------------------------------------------------------------------------
__global__ __launch_bounds__(256) void prep_kernel(
    const float* __restrict__ x, const float* __restrict__ w,
    const float* __restrict__ Y,
    __hip_bfloat16* __restrict__ psi_t, __hip_bfloat16* __restrict__ x_t)
{
  __shared__ float smem[8256];
  const int t = threadIdx.x;

  if (blockIdx.x < 64) {
    const int g    = blockIdx.x;
    const int wv   = t >> 6, lane = t & 63;
    const int ln15 = lane & 15, quad = lane >> 4;

    floatx4 acc[2][4] = {};   // [i-tile][e-tile], statically indexed

    for (int n0 = 0; n0 < 512; n0 += 64) {
      __syncthreads();
      {
        const float4* src = (const float4*)(Y + n0*121);
        float4* dst = (float4*)smem;
        for (int idx = t; idx < 1936; idx += 256) dst[idx] = src[idx];
      }
      __syncthreads();

      #pragma unroll
      for (int ks = 0; ks < 2; ++ks) {
        const int kb = ks*32 + quad*8;

        bf16x8 ahi[2], alo[2];
        #pragma unroll
        for (int ti = 0; ti < 2; ++ti) {
          const int irow = (wv << 5) + (ti << 4) + ln15;
          #pragma unroll
          for (int j = 0; j < 8; ++j) {
            float v = smem[(kb + j)*121 + irow];
            __hip_bfloat16 h = __float2bfloat16(v);
            float hf = __bfloat162float(h);
            __hip_bfloat16 lo = __float2bfloat16(v - hf);
            ahi[ti][j] = *(short*)&h;
            alo[ti][j] = *(short*)&lo;
          }
        }

        bf16x8 bhi[4], blo[4];
        #pragma unroll
        for (int te = 0; te < 4; ++te) {
          const int e = (te << 4) + ln15;
          const float* wp = w + ((e << 6) + g)*512 + n0 + kb;
          float4 wa = *(const float4*)wp;
          float4 wb = *(const float4*)(wp + 4);
          float v[8] = {wa.x, wa.y, wa.z, wa.w, wb.x, wb.y, wb.z, wb.w};
          #pragma unroll
          for (int j = 0; j < 8; ++j) {
            __hip_bfloat16 h = __float2bfloat16(v[j]);
            float hf = __bfloat162float(h);
            __hip_bfloat16 lo = __float2bfloat16(v[j] - hf);
            bhi[te][j] = *(short*)&h;
            blo[te][j] = *(short*)&lo;
          }
        }

        #pragma unroll
        for (int ti = 0; ti < 2; ++ti) {
          #pragma unroll
          for (int te = 0; te < 4; ++te) {
            acc[ti][te] = __builtin_amdgcn_mfma_f32_16x16x32_bf16(ahi[ti], bhi[te], acc[ti][te], 0, 0, 0);
            acc[ti][te] = __builtin_amdgcn_mfma_f32_16x16x32_bf16(ahi[ti], blo[te], acc[ti][te], 0, 0, 0);
            acc[ti][te] = __builtin_amdgcn_mfma_f32_16x16x32_bf16(alo[ti], bhi[te], acc[ti][te], 0, 0, 0);
          }
        }
      }
    }

    const float scale = 0.00552427172801990267f;  // 1/(8*sqrt(512))
    #pragma unroll
    for (int ti = 0; ti < 2; ++ti) {
      #pragma unroll
      for (int rr = 0; rr < 4; ++rr) {
        const int i = (wv << 5) + (ti << 4) + (quad << 2) + rr;
        if (i < 121) {
          int l = c_ltab[i];
          int d = 2*l + 1;
          int row = 64*l*l + g*d + (i - l*l);
          #pragma unroll
          for (int te = 0; te < 4; ++te) {
            __hip_bfloat16 hv = __float2bfloat16(acc[ti][te][rr] * scale);
            psi_t[row*64 + (te << 4) + ln15] = hv;
          }
        }
      }
    }
  } else {
    const int b = blockIdx.x - 64;
    {
      const float4* src = (const float4*)(x + b*7744);
      float4* dst = (float4*)smem;
      for (int idx = t; idx < 1936; idx += 256) dst[idx] = src[idx];
    }
    __syncthreads();
    const int wv = t >> 6, lane = t & 63;
    for (int ii = wv; ii < 121; ii += 4) {
      int l = c_ltab[ii];
      int d = 2*l + 1;
      int row = 512*l*l + b*d + (ii - l*l);
      x_t[row*64 + lane] = __float2bfloat16(smem[lane*121 + ii]);
    }
  }
}

// ---------------------------------------------------------------------------
// Conv: per-l GEMM with (g,b)-aligned tiles. Template on L so all divides are
// compile-time. Block = GT whole g's (GT*d<=64 p-rows) x BT whole b's
// (BT*d<=256 q-cols), K=64. Accumulators staged in LDS [64][258], epilogue
// writes complete d^2 runs per (b,g) -> 256B/instr coalesced stores.
// ---------------------------------------------------------------------------
#define LPITCH 258   // row stride (f32 words); 4*258 % 32 == 8 -> uniform 2-way LDS (free)

template <int L>
__device__ void conv_body(int r, int t,
                          const ushort* __restrict__ psi,
                          const ushort* __restrict__ xt,
                          float* __restrict__ out, float* lt)
{
  constexpr int d    = 2*L + 1;
  constexpr int dd   = d*d;
  constexpr int GT   = 64  / d;            // whole g's per block
  constexpr int BT   = 256 / d;            // whole b's per block
  constexpr int NBT  = (512 + BT - 1) / BT;
  constexpr int OFFL = L*(2*L - 1)*(2*L + 1)/3;   // sum_{k<L} (2k+1)^2

  const int wv = t >> 6, lane = t & 63;
  const int ln15 = lane & 15, quad = lane >> 4;

  const int gtI = r / NBT;                 // compile-time magic div
  const int btI = r - gtI*NBT;
  const int g0 = gtI*GT, b0 = btI*BT;

  // ---- MFMA phase: 64 p-rows x 256 q-cols, K=64 ----
  int pr = g0*d + wv*16 + ln15;
  if (pr > 64*d - 1) pr = 64*d - 1;        // edge clamp (garbage masked in epilogue)
  const ushort* psiRow = psi + (64*L*L + pr)*64 + quad*8;
  const bf16x8 af0 = *(const bf16x8*)(psiRow);
  const bf16x8 af1 = *(const bf16x8*)(psiRow + 32);

  const ushort* xbase = xt + 512*L*L*64 + quad*8;

  #pragma unroll 4
  for (int qq = 0; qq < 16; ++qq) {
    int qr = b0*d + qq*16 + ln15;
    if (qr > 512*d - 1) qr = 512*d - 1;
    const ushort* xr = xbase + qr*64;
    bf16x8 bf0 = *(const bf16x8*)(xr);
    bf16x8 bf1 = *(const bf16x8*)(xr + 32);
    floatx4 acc = {0.f, 0.f, 0.f, 0.f};
    acc = __builtin_amdgcn_mfma_f32_16x16x32_bf16(af0, bf0, acc, 0, 0, 0);
    acc = __builtin_amdgcn_mfma_f32_16x16x32_bf16(af1, bf1, acc, 0, 0, 0);
    // D layout: col = ln15 (q), row = quad*4+rr (p)
    float* dst = lt + (wv*16 + quad*4)*LPITCH + qq*16 + ln15;
    #pragma unroll
    for (int rr = 0; rr < 4; ++rr) dst[rr*LPITCH] = acc[rr];
  }
  __syncthreads();

  // ---- Epilogue: complete d^2 runs per (b,g), contiguous stores ----
  if constexpr (dd >= 64) {
    // one (b,g) pair per wave-iteration; lanes sweep o = u*d+m (out-contiguous)
    for (int pp = wv; pp < GT*BT; pp += 4) {
      const int g_i = pp / BT;             // wave-uniform scalar div
      const int b_i = pp - g_i*BT;
      const int g = g0 + g_i, b = b0 + b_i;
      if (g >= 64 || b >= 512) continue;
      const int obase = b*OUTB + g*OUTROW + OFFL;
      const float* lrow = lt + (g_i*d)*LPITCH + b_i*d;
      #pragma unroll
      for (int o0 = 0; o0 < dd; o0 += 64) {
        int o = o0 + lane;
        if (o < dd) {
          int u = o / d;                   // compile-time magic
          int m = o - u*d;
          out[obase + o] = lrow[u*LPITCH + m];
        }
      }
    }
  } else {
    // multiple pairs per instruction (small d): lane -> (pair, o)
    constexpr int PPI = 64 / dd;
    const int pq = lane / dd;              // compile-time magic
    const int o  = lane - pq*dd;
    const int u  = o / d;
    const int m  = o - u*d;
    for (int base = wv*PPI; base < GT*BT; base += 4*PPI) {
      int pp = base + pq;
      if (pq < PPI && pp < GT*BT) {
        int g_i = pp / BT;
        int b_i = pp - g_i*BT;
        int g = g0 + g_i, b = b0 + b_i;
        if (g < 64 && b < 512)
          out[b*OUTB + g*OUTROW + OFFL + o] = lt[(g_i*d + u)*LPITCH + b_i*d + m];
      }
    }
  }
}

__global__ __launch_bounds__(256) void conv_kernel(
    const __hip_bfloat16* __restrict__ psi_t,
    const __hip_bfloat16* __restrict__ x_t,
    float* __restrict__ out)
{
  __shared__ float lt[64*LPITCH];          // 66 KB -> 2 blocks/CU

  // bijective XCD swizzle (NWG=4229 = 8*528+5): each XCD gets a contiguous range
  const int orig = blockIdx.x;
  const int xcd = orig & 7, idx = orig >> 3;
  const int bid = (xcd < 5 ? xcd*529 : 2645 + (xcd - 5)*528) + idx;

  int l = 0;
  #pragma unroll
  for (int ll = 1; ll <= 10; ++ll)
    if (bid >= c_blk[ll]) l = ll;
  const int r = bid - c_blk[l];

  const ushort* psi = (const ushort*)psi_t;
  const ushort* xt  = (const ushort*)x_t;
  const int t = threadIdx.x;

  switch (l) {
    case 0:  conv_body<0 >(r, t, psi, xt, out, lt); break;
    case 1:  conv_body<1 >(r, t, psi, xt, out, lt); break;
    case 2:  conv_body<2 >(r, t, psi, xt, out, lt); break;
    case 3:  conv_body<3 >(r, t, psi, xt, out, lt); break;
    case 4:  conv_body<4 >(r, t, psi, xt, out, lt); break;
    case 5:  conv_body<5 >(r, t, psi, xt, out, lt); break;
    case 6:  conv_body<6 >(r, t, psi, xt, out, lt); break;
    case 7:  conv_body<7 >(r, t, psi, xt, out, lt); break;
    case 8:  conv_body<8 >(r, t, psi, xt, out, lt); break;
    case 9:  conv_body<9 >(r, t, psi, xt, out, lt); break;
    default: conv_body<10>(r, t, psi, xt, out, lt); break;
  }
}

extern "C" void kernel_launch(void* const* d_in, const int* in_sizes, int n_in,
                              void* d_out, int out_size, void* d_ws, size_t ws_size,
                              hipStream_t stream) {
  const float* x = (const float*)d_in[0];   // 512*64*121
  const float* w = (const float*)d_in[1];   // 64*64*512
  const float* Y = (const float*)d_in[2];   // 512*121
  float* out = (float*)d_out;               // 512*64*1771

  __hip_bfloat16* psi_t = (__hip_bfloat16*)d_ws;                       // 7744*64 bf16 (<1MB)
  __hip_bfloat16* x_t   = (__hip_bfloat16*)((char*)d_ws + (1 << 20));  // 61952*64 bf16 (~7.9MB)

  prep_kernel<<<576, 256, 0, stream>>>(x, w, Y, psi_t, x_t);
  conv_kernel<<<4229, 256, 0, stream>>>(psi_t, x_t, out);
}

// Round 3
// 358.339 us; speedup vs baseline: 1.0496x; 1.0496x over previous
//
#include <hip/hip_runtime.h>
#include <hip/hip_bf16.h>

// S2Conv: x (512,64,121) f32, w (64,64,512) f32, Y (512,121) f32
// out (512,64,1771) f32.
// psi[e,g,i] = sum_n Y[n,i] w[e,g,n] / sqrt(512)
// out[b,g, OFF_l + u*d + m] = (1/8) sum_e psi[e,g,l^2+u] * x[b,e,l^2+m]
//
// Round 3: SINGLE-VARIABLE edit vs round 2 — conv blocks go 256 -> 512
// threads (8 waves; each wave handles half the q-range), restoring occupancy
// to 2 blocks x 512 thr = 16 waves/CU (4/SIMD) at the same 66 KB LDS.
// Tile geometry, LDS layout, epilogue store addresses, XCD swizzle, and all
// arithmetic identical to round 2 (absmax must stay 0.03125).

#define OUTROW 1771
#define OUTB   113344  // 64*1771

typedef __attribute__((ext_vector_type(8))) short bf16x8;
typedef __attribute__((ext_vector_type(4))) float floatx4;

// cumulative conv block counts per l (NGT*NBT): {2,28,66,120,190,299,432,496,770,880,946}
__device__ __constant__ int c_blk[12] = {0,2,30,96,216,406,705,1137,1633,2403,3283,4229};
__device__ __constant__ signed char c_ltab[121] = {
  0,
  1,1,1,
  2,2,2,2,2,
  3,3,3,3,3,3,3,
  4,4,4,4,4,4,4,4,4,
  5,5,5,5,5,5,5,5,5,5,5,
  6,6,6,6,6,6,6,6,6,6,6,6,6,
  7,7,7,7,7,7,7,7,7,7,7,7,7,7,7,
  8,8,8,8,8,8,8,8,8,8,8,8,8,8,8,8,8,
  9,9,9,9,9,9,9,9,9,9,9,9,9,9,9,9,9,9,9,
  10,10,10,10,10,10,10,10,10,10,10,10,10,10,10,10,10,10,10,10,10
};

// ---------------------------------------------------------------------------
// Prep (unchanged): blocks [0,64): psi via MFMA, one block per g.
//                   blocks [64,576): x_t transpose, one block per b.
// psi_t[64*l^2 + g*d + u][e] = scale * sum_n w[e,g,n]*Y[n,l^2+u]   (bf16)
// x_t [512*l^2 + b*d + m][e] = x[b,e,l^2+m]                        (bf16)
// ---------------------------------------------------------------------------
__global__ __launch_bounds__(256) void prep_kernel(
    const float* __restrict__ x, const float* __restrict__ w,
    const float* __restrict__ Y,
    __hip_bfloat16* __restrict__ psi_t, __hip_bfloat16* __restrict__ x_t)
{
  __shared__ float smem[8256];
  const int t = threadIdx.x;

  if (blockIdx.x < 64) {
    const int g    = blockIdx.x;
    const int wv   = t >> 6, lane = t & 63;
    const int ln15 = lane & 15, quad = lane >> 4;

    floatx4 acc[2][4] = {};   // [i-tile][e-tile], statically indexed

    for (int n0 = 0; n0 < 512; n0 += 64) {
      __syncthreads();
      {
        const float4* src = (const float4*)(Y + n0*121);
        float4* dst = (float4*)smem;
        for (int idx = t; idx < 1936; idx += 256) dst[idx] = src[idx];
      }
      __syncthreads();

      #pragma unroll
      for (int ks = 0; ks < 2; ++ks) {
        const int kb = ks*32 + quad*8;

        bf16x8 ahi[2], alo[2];
        #pragma unroll
        for (int ti = 0; ti < 2; ++ti) {
          const int irow = (wv << 5) + (ti << 4) + ln15;
          #pragma unroll
          for (int j = 0; j < 8; ++j) {
            float v = smem[(kb + j)*121 + irow];
            __hip_bfloat16 h = __float2bfloat16(v);
            float hf = __bfloat162float(h);
            __hip_bfloat16 lo = __float2bfloat16(v - hf);
            ahi[ti][j] = *(short*)&h;
            alo[ti][j] = *(short*)&lo;
          }
        }

        bf16x8 bhi[4], blo[4];
        #pragma unroll
        for (int te = 0; te < 4; ++te) {
          const int e = (te << 4) + ln15;
          const float* wp = w + ((e << 6) + g)*512 + n0 + kb;
          float4 wa = *(const float4*)wp;
          float4 wb = *(const float4*)(wp + 4);
          float v[8] = {wa.x, wa.y, wa.z, wa.w, wb.x, wb.y, wb.z, wb.w};
          #pragma unroll
          for (int j = 0; j < 8; ++j) {
            __hip_bfloat16 h = __float2bfloat16(v[j]);
            float hf = __bfloat162float(h);
            __hip_bfloat16 lo = __float2bfloat16(v[j] - hf);
            bhi[te][j] = *(short*)&h;
            blo[te][j] = *(short*)&lo;
          }
        }

        #pragma unroll
        for (int ti = 0; ti < 2; ++ti) {
          #pragma unroll
          for (int te = 0; te < 4; ++te) {
            acc[ti][te] = __builtin_amdgcn_mfma_f32_16x16x32_bf16(ahi[ti], bhi[te], acc[ti][te], 0, 0, 0);
            acc[ti][te] = __builtin_amdgcn_mfma_f32_16x16x32_bf16(ahi[ti], blo[te], acc[ti][te], 0, 0, 0);
            acc[ti][te] = __builtin_amdgcn_mfma_f32_16x16x32_bf16(alo[ti], bhi[te], acc[ti][te], 0, 0, 0);
          }
        }
      }
    }

    const float scale = 0.00552427172801990267f;  // 1/(8*sqrt(512))
    #pragma unroll
    for (int ti = 0; ti < 2; ++ti) {
      #pragma unroll
      for (int rr = 0; rr < 4; ++rr) {
        const int i = (wv << 5) + (ti << 4) + (quad << 2) + rr;
        if (i < 121) {
          int l = c_ltab[i];
          int d = 2*l + 1;
          int row = 64*l*l + g*d + (i - l*l);
          #pragma unroll
          for (int te = 0; te < 4; ++te) {
            __hip_bfloat16 hv = __float2bfloat16(acc[ti][te][rr] * scale);
            psi_t[row*64 + (te << 4) + ln15] = hv;
          }
        }
      }
    }
  } else {
    const int b = blockIdx.x - 64;
    {
      const float4* src = (const float4*)(x + b*7744);
      float4* dst = (float4*)smem;
      for (int idx = t; idx < 1936; idx += 256) dst[idx] = src[idx];
    }
    __syncthreads();
    const int wv = t >> 6, lane = t & 63;
    for (int ii = wv; ii < 121; ii += 4) {
      int l = c_ltab[ii];
      int d = 2*l + 1;
      int row = 512*l*l + b*d + (ii - l*l);
      x_t[row*64 + lane] = __float2bfloat16(smem[lane*121 + ii]);
    }
  }
}

// ---------------------------------------------------------------------------
// Conv: per-l GEMM with (g,b)-aligned tiles, 512-thread blocks (8 waves).
// Wave wv: wslot = wv&3 owns p-rows [wslot*16,+16); qhalf = wv>>2 owns
// q-cols [qhalf*128,+128). Same 64x256 tile, LDS [64][258] f32, same
// epilogue (complete d^2 runs per (b,g)) as round 2.
// ---------------------------------------------------------------------------
#define LPITCH 258   // row stride (f32 words); uniform <=2-way LDS (free)

template <int L>
__device__ void conv_body(int r, int t,
                          const ushort* __restrict__ psi,
                          const ushort* __restrict__ xt,
                          float* __restrict__ out, float* lt)
{
  constexpr int d    = 2*L + 1;
  constexpr int dd   = d*d;
  constexpr int GT   = 64  / d;            // whole g's per block
  constexpr int BT   = 256 / d;            // whole b's per block
  constexpr int NBT  = (512 + BT - 1) / BT;
  constexpr int OFFL = L*(2*L - 1)*(2*L + 1)/3;   // sum_{k<L} (2k+1)^2

  const int wv = t >> 6, lane = t & 63;
  const int wslot = wv & 3, qhalf = wv >> 2;
  const int ln15 = lane & 15, quad = lane >> 4;

  const int gtI = r / NBT;                 // compile-time magic div
  const int btI = r - gtI*NBT;
  const int g0 = gtI*GT, b0 = btI*BT;

  // ---- MFMA phase: 64 p-rows x 256 q-cols, K=64; this wave: 16p x 128q ----
  int pr = g0*d + wslot*16 + ln15;
  if (pr > 64*d - 1) pr = 64*d - 1;        // edge clamp (garbage masked in epilogue)
  const ushort* psiRow = psi + (64*L*L + pr)*64 + quad*8;
  const bf16x8 af0 = *(const bf16x8*)(psiRow);
  const bf16x8 af1 = *(const bf16x8*)(psiRow + 32);

  const ushort* xbase = xt + 512*L*L*64 + quad*8;

  #pragma unroll 4
  for (int qi = 0; qi < 8; ++qi) {
    const int qq = qhalf*8 + qi;
    int qr = b0*d + qq*16 + ln15;
    if (qr > 512*d - 1) qr = 512*d - 1;
    const ushort* xr = xbase + qr*64;
    bf16x8 bf0 = *(const bf16x8*)(xr);
    bf16x8 bf1 = *(const bf16x8*)(xr + 32);
    floatx4 acc = {0.f, 0.f, 0.f, 0.f};
    acc = __builtin_amdgcn_mfma_f32_16x16x32_bf16(af0, bf0, acc, 0, 0, 0);
    acc = __builtin_amdgcn_mfma_f32_16x16x32_bf16(af1, bf1, acc, 0, 0, 0);
    // D layout: col = ln15 (q), row = quad*4+rr (p)
    float* dst = lt + (wslot*16 + quad*4)*LPITCH + qq*16 + ln15;
    #pragma unroll
    for (int rr = 0; rr < 4; ++rr) dst[rr*LPITCH] = acc[rr];
  }
  __syncthreads();

  // ---- Epilogue: complete d^2 runs per (b,g), contiguous stores; 8 waves ----
  if constexpr (dd >= 64) {
    for (int pp = wv; pp < GT*BT; pp += 8) {
      const int g_i = pp / BT;             // wave-uniform scalar div
      const int b_i = pp - g_i*BT;
      const int g = g0 + g_i, b = b0 + b_i;
      if (g >= 64 || b >= 512) continue;
      const int obase = b*OUTB + g*OUTROW + OFFL;
      const float* lrow = lt + (g_i*d)*LPITCH + b_i*d;
      #pragma unroll
      for (int o0 = 0; o0 < dd; o0 += 64) {
        int o = o0 + lane;
        if (o < dd) {
          int u = o / d;                   // compile-time magic
          int m = o - u*d;
          out[obase + o] = lrow[u*LPITCH + m];
        }
      }
    }
  } else {
    constexpr int PPI = 64 / dd;
    const int pq = lane / dd;              // compile-time magic
    const int o  = lane - pq*dd;
    const int u  = o / d;
    const int m  = o - u*d;
    for (int base = wv*PPI; base < GT*BT; base += 8*PPI) {
      int pp = base + pq;
      if (pq < PPI && pp < GT*BT) {
        int g_i = pp / BT;
        int b_i = pp - g_i*BT;
        int g = g0 + g_i, b = b0 + b_i;
        if (g < 64 && b < 512)
          out[b*OUTB + g*OUTROW + OFFL + o] = lt[(g_i*d + u)*LPITCH + b_i*d + m];
      }
    }
  }
}

__global__ __launch_bounds__(512) void conv_kernel(
    const __hip_bfloat16* __restrict__ psi_t,
    const __hip_bfloat16* __restrict__ x_t,
    float* __restrict__ out)
{
  __shared__ float lt[64*LPITCH];          // 66 KB -> 2 blocks x 512 thr = 16 waves/CU

  // bijective XCD swizzle (NWG=4229 = 8*528+5): each XCD gets a contiguous range
  const int orig = blockIdx.x;
  const int xcd = orig & 7, idx = orig >> 3;
  const int bid = (xcd < 5 ? xcd*529 : 2645 + (xcd - 5)*528) + idx;

  int l = 0;
  #pragma unroll
  for (int ll = 1; ll <= 10; ++ll)
    if (bid >= c_blk[ll]) l = ll;
  const int r = bid - c_blk[l];

  const ushort* psi = (const ushort*)psi_t;
  const ushort* xt  = (const ushort*)x_t;
  const int t = threadIdx.x;

  switch (l) {
    case 0:  conv_body<0 >(r, t, psi, xt, out, lt); break;
    case 1:  conv_body<1 >(r, t, psi, xt, out, lt); break;
    case 2:  conv_body<2 >(r, t, psi, xt, out, lt); break;
    case 3:  conv_body<3 >(r, t, psi, xt, out, lt); break;
    case 4:  conv_body<4 >(r, t, psi, xt, out, lt); break;
    case 5:  conv_body<5 >(r, t, psi, xt, out, lt); break;
    case 6:  conv_body<6 >(r, t, psi, xt, out, lt); break;
    case 7:  conv_body<7 >(r, t, psi, xt, out, lt); break;
    case 8:  conv_body<8 >(r, t, psi, xt, out, lt); break;
    case 9:  conv_body<9 >(r, t, psi, xt, out, lt); break;
    default: conv_body<10>(r, t, psi, xt, out, lt); break;
  }
}

extern "C" void kernel_launch(void* const* d_in, const int* in_sizes, int n_in,
                              void* d_out, int out_size, void* d_ws, size_t ws_size,
                              hipStream_t stream) {
  const float* x = (const float*)d_in[0];   // 512*64*121
  const float* w = (const float*)d_in[1];   // 64*64*512
  const float* Y = (const float*)d_in[2];   // 512*121
  float* out = (float*)d_out;               // 512*64*1771

  __hip_bfloat16* psi_t = (__hip_bfloat16*)d_ws;                       // 7744*64 bf16 (<1MB)
  __hip_bfloat16* x_t   = (__hip_bfloat16*)((char*)d_ws + (1 << 20));  // 61952*64 bf16 (~7.9MB)

  prep_kernel<<<576, 256, 0, stream>>>(x, w, Y, psi_t, x_t);
  conv_kernel<<<4229, 512, 0, stream>>>(psi_t, x_t, out);
}